// Round 7
// baseline (5341.633 us; speedup 1.0000x reference)
//
#include <hip/hip_runtime.h>

#define Bsz 2048
#define Ssz 96
#define Fsz 32
#define Hsz 256
#define Osz 6
#define LAsz 32
#define RT 8                  // batch rows per block; grid = 256 = 1 block/CU
#define NSTEP (Ssz + LAsz)
#define NTHR 512              // thread = (gate-channel j, K-half q); 8 waves = 2/SIMD

// ---------- accurate f64 exp (|rel err| ~1e-14) ----------
__device__ __forceinline__ double exp_d(double x) {
    x = fmin(fmax(x, -700.0), 700.0);
    const double LOG2E = 1.4426950408889634074;
    const double LN2HI = 6.93147180369123816490e-01;
    const double LN2LO = 1.90821492927058770002e-10;
    double n = __builtin_rint(x * LOG2E);
    double r = fma(-n, LN2HI, x);
    r = fma(-n, LN2LO, r);
    double p = 2.5052108385441718775e-08;
    p = fma(p, r, 2.7557319223985890653e-07);
    p = fma(p, r, 2.7557319223985892511e-06);
    p = fma(p, r, 2.4801587301587301566e-05);
    p = fma(p, r, 1.9841269841269841253e-04);
    p = fma(p, r, 1.3888888888888889419e-03);
    p = fma(p, r, 8.3333333333333332177e-03);
    p = fma(p, r, 4.1666666666666664354e-02);
    p = fma(p, r, 1.6666666666666665741e-01);
    p = fma(p, r, 5.0e-01);
    p = fma(p, r, 1.0);
    p = fma(p, r, 1.0);
    long long bits = (long long)(1023 + (int)n) << 52;
    return p * __longlong_as_double(bits);
}

// f64 reciprocal via f32 seed + 3 Newton steps (~0.5 ulp), avoids slow f64 div
__device__ __forceinline__ double recip_d(double y) {
    double r = (double)(1.0f / (float)y);
    r = fma(fma(-y, r, 1.0), r, r);
    r = fma(fma(-y, r, 1.0), r, r);
    r = fma(fma(-y, r, 1.0), r, r);
    return r;
}
__device__ __forceinline__ double sigmoid_d(double x) { return recip_d(1.0 + exp_d(-x)); }
__device__ __forceinline__ double tanh_d(double x) {
    double ax = fabs(x);
    double t = exp_d(-2.0 * ax);
    double r = (1.0 - t) * recip_d(1.0 + t);
    return x >= 0.0 ? r : -r;
}

// ---------- pre-pass: transpose weights into k-major float4 tiles ----------
__global__ void transpose_w(const float* __restrict__ W_ih,
                            const float* __restrict__ W_hh,
                            float4* __restrict__ wihT,
                            float4* __restrict__ whhT)
{
    int i = blockIdx.x * 256 + threadIdx.x;   // 1024 * 72 total
    if (i >= 1024 * 72) return;
    int gr = i / 72, s = i - gr * 72;
    if (s < 8) {
        const float* p = W_ih + (size_t)gr * Fsz + s * 4;
        wihT[s * 1024 + gr] = make_float4(p[0], p[1], p[2], p[3]);
    } else {
        int k4 = s - 8;
        const float* p = W_hh + (size_t)gr * Hsz + k4 * 4;
        whhT[k4 * 1024 + gr] = make_float4(p[0], p[1], p[2], p[3]);
    }
}

// 8 ascending-k FMAs for gate g, row r
#define DOT8(accv, WA, WB)                              \
    accv = fma((double)WA.x, h01.x, accv);              \
    accv = fma((double)WA.y, h01.y, accv);              \
    accv = fma((double)WA.z, h23.x, accv);              \
    accv = fma((double)WA.w, h23.y, accv);              \
    accv = fma((double)WB.x, h45.x, accv);              \
    accv = fma((double)WB.y, h45.y, accv);              \
    accv = fma((double)WB.z, h67.x, accv);              \
    accv = fma((double)WB.w, h67.y, accv);

__global__ __launch_bounds__(NTHR, 2) void lstm_persist(
    const float* __restrict__ x,
    const float4* __restrict__ wihT, const float4* __restrict__ whhT,
    const float* __restrict__ b_ih, const float* __restrict__ b_hh,
    const float* __restrict__ W_fc, const float* __restrict__ b_fc,
    float* __restrict__ out)
{
    __shared__ __align__(16) double h_lds[RT][Hsz];     // 16 KB
    __shared__ __align__(16) double x_lds[RT][Fsz];     // 2 KB
    __shared__ double o_lds[RT][Osz];
    __shared__ float  wfc_lds[Osz * Hsz];               // 6 KB
    __shared__ double xch[2][16][Hsz + 1];              // 65.8 KB partial-gate exchange

    const int tid  = threadIdx.x;
    const int row0 = blockIdx.x * RT;
    const int j    = tid & (Hsz - 1);                    // gate-channel owned
    const int q    = tid >> 8;                           // K-half: 0 or 1

    for (int i = tid; i < RT * Hsz; i += NTHR) ((double*)h_lds)[i] = 0.0;
    for (int i = tid; i < Osz * Hsz; i += NTHR) wfc_lds[i] = W_fc[i];

    const double bias0 = (double)b_ih[0 * Hsz + j] + (double)b_hh[0 * Hsz + j];
    const double bias1 = (double)b_ih[1 * Hsz + j] + (double)b_hh[1 * Hsz + j];
    const double bias2 = (double)b_ih[2 * Hsz + j] + (double)b_hh[2 * Hsz + j];
    const double bias3 = (double)b_ih[3 * Hsz + j] + (double)b_hh[3 * Hsz + j];

    const int rbase = q ? 4 : 0;     // rows this thread finalizes
    const int hk_begin = q ? 112 : 0;
    const int hk_end   = q ? Hsz : 112;

    double c_reg[4];                 // c for finalized rows rbase..rbase+3
    #pragma unroll
    for (int r = 0; r < 4; ++r) c_reg[r] = 0.0;

    __syncthreads();

    for (int t = 0; t < NSTEP; ++t) {
        // ---- stage x[:, t (or t-Ssz), :]; fuse look-ahead o replacement ----
        if (tid < RT * Fsz) {
            int r = tid >> 5, f = tid & 31;
            int ts = (t < Ssz) ? t : (t - Ssz);
            double v;
            if (t >= Ssz && f < Osz) v = o_lds[r][f];
            else v = (double)x[((size_t)(row0 + r) * Ssz + ts) * Fsz + f];
            x_lds[r][f] = v;
        }
        __syncthreads();                                 // A: x staged, h final

        double acc[4][RT];
        #pragma unroll
        for (int r = 0; r < RT; ++r) {
            bool own = (r >= rbase) && (r < rbase + 4);
            acc[0][r] = own ? bias0 : 0.0;
            acc[1][r] = own ? bias1 : 0.0;
            acc[2][r] = own ? bias2 : 0.0;
            acc[3][r] = own ? bias3 : 0.0;
        }

        // ---- F part (khalf 0 only): gates += W_ih . x ----
        if (q == 0) {
            #pragma unroll 1
            for (int k0 = 0; k0 < Fsz; k0 += 8) {
                const int s = k0 >> 2;
                float4 wa[4], wb[4];
                #pragma unroll
                for (int g = 0; g < 4; ++g) {
                    wa[g] = wihT[(size_t)s * 1024 + (g << 8) + j];
                    wb[g] = wihT[(size_t)(s + 1) * 1024 + (g << 8) + j];
                }
                #pragma unroll
                for (int r = 0; r < RT; ++r) {
                    double2 h01 = *(const double2*)&x_lds[r][k0];
                    double2 h23 = *(const double2*)&x_lds[r][k0 + 2];
                    double2 h45 = *(const double2*)&x_lds[r][k0 + 4];
                    double2 h67 = *(const double2*)&x_lds[r][k0 + 6];
                    DOT8(acc[0][r], wa[0], wb[0]);
                    DOT8(acc[1][r], wa[1], wb[1]);
                    DOT8(acc[2][r], wa[2], wb[2]);
                    DOT8(acc[3][r], wa[3], wb[3]);
                }
            }
        }

        // ---- H part: this K-half's slice of gates += W_hh . h ----
        #pragma unroll 1
        for (int k0 = hk_begin; k0 < hk_end; k0 += 8) {
            const int s = k0 >> 2;
            float4 wa[4], wb[4];
            #pragma unroll
            for (int g = 0; g < 4; ++g) {
                wa[g] = whhT[(size_t)s * 1024 + (g << 8) + j];
                wb[g] = whhT[(size_t)(s + 1) * 1024 + (g << 8) + j];
            }
            #pragma unroll
            for (int r = 0; r < RT; ++r) {
                double2 h01 = *(const double2*)&h_lds[r][k0];
                double2 h23 = *(const double2*)&h_lds[r][k0 + 2];
                double2 h45 = *(const double2*)&h_lds[r][k0 + 4];
                double2 h67 = *(const double2*)&h_lds[r][k0 + 6];
                DOT8(acc[0][r], wa[0], wb[0]);
                DOT8(acc[1][r], wa[1], wb[1]);
                DOT8(acc[2][r], wa[2], wb[2]);
                DOT8(acc[3][r], wa[3], wb[3]);
            }
        }

        // ---- write partials for the rows the OTHER half finalizes ----
        {
            const int rother = q ? 0 : 4;
            #pragma unroll
            for (int g = 0; g < 4; ++g)
                #pragma unroll
                for (int rr = 0; rr < 4; ++rr)
                    xch[q][g * 4 + rr][j] = acc[g][rother + rr];
        }
        __syncthreads();                                 // B: dots done, partials published

        // ---- combine + activations; update c (regs) and h (LDS) ----
        {
            const int other = 1 - q;
            #pragma unroll
            for (int rr = 0; rr < 4; ++rr) {
                double t0 = acc[0][rbase + rr] + xch[other][0 * 4 + rr][j];
                double t1 = acc[1][rbase + rr] + xch[other][1 * 4 + rr][j];
                double t2 = acc[2][rbase + rr] + xch[other][2 * 4 + rr][j];
                double t3 = acc[3][rbase + rr] + xch[other][3 * 4 + rr][j];
                double si = sigmoid_d(t0);
                double sf = sigmoid_d(t1);
                double tg = tanh_d(t2);
                double so = sigmoid_d(t3);
                double cn = fma(sf, c_reg[rr], si * tg);
                c_reg[rr] = cn;
                h_lds[rbase + rr][j] = so * tanh_d(cn);
            }
        }

        // ---- readout: wave w owns row w (8 waves, 8 rows) ----
        if (t >= Ssz - 1) {
            __syncthreads();                              // C: h complete
            const int w    = tid >> 6;                    // row 0..7
            const int lane = tid & 63;
            double a0 = 0.0, a1 = 0.0, a2 = 0.0, a3 = 0.0, a4 = 0.0, a5 = 0.0;
            #pragma unroll
            for (int m = 0; m < 4; ++m) {
                int k = lane + 64 * m;
                double hv = h_lds[w][k];
                bool b = hv > 0.0;
                a0 += b ? (double)wfc_lds[0 * Hsz + k] : 0.0;
                a1 += b ? (double)wfc_lds[1 * Hsz + k] : 0.0;
                a2 += b ? (double)wfc_lds[2 * Hsz + k] : 0.0;
                a3 += b ? (double)wfc_lds[3 * Hsz + k] : 0.0;
                a4 += b ? (double)wfc_lds[4 * Hsz + k] : 0.0;
                a5 += b ? (double)wfc_lds[5 * Hsz + k] : 0.0;
            }
            #pragma unroll
            for (int off = 32; off >= 1; off >>= 1) {
                a0 += __shfl_down(a0, off, 64);
                a1 += __shfl_down(a1, off, 64);
                a2 += __shfl_down(a2, off, 64);
                a3 += __shfl_down(a3, off, 64);
                a4 += __shfl_down(a4, off, 64);
                a5 += __shfl_down(a5, off, 64);
            }
            if (lane == 0) {
                size_t base = ((size_t)(row0 + w) * (LAsz + 1) + (t - (Ssz - 1))) * Osz;
                double o;
                o = (double)b_fc[0] + a0; o_lds[w][0] = o; out[base + 0] = (float)o;
                o = (double)b_fc[1] + a1; o_lds[w][1] = o; out[base + 1] = (float)o;
                o = (double)b_fc[2] + a2; o_lds[w][2] = o; out[base + 2] = (float)o;
                o = (double)b_fc[3] + a3; o_lds[w][3] = o; out[base + 3] = (float)o;
                o = (double)b_fc[4] + a4; o_lds[w][4] = o; out[base + 4] = (float)o;
                o = (double)b_fc[5] + a5; o_lds[w][5] = o; out[base + 5] = (float)o;
            }
            __syncthreads();                              // D: o_lds published
        }
        // non-readout steps: next iteration's barrier A orders h/xch writes vs reads
    }
}

extern "C" void kernel_launch(void* const* d_in, const int* in_sizes, int n_in,
                              void* d_out, int out_size, void* d_ws, size_t ws_size,
                              hipStream_t stream)
{
    const float* x    = (const float*)d_in[0];
    const float* W_ih = (const float*)d_in[1];
    const float* W_hh = (const float*)d_in[2];
    const float* b_ih = (const float*)d_in[3];
    const float* b_hh = (const float*)d_in[4];
    const float* W_fc = (const float*)d_in[5];
    const float* b_fc = (const float*)d_in[6];
    float* out = (float*)d_out;

    float4* whhT = (float4*)d_ws;                 // 64*1024 float4 = 1 MB
    float4* wihT = whhT + 64 * 1024;              // 8*1024 float4 = 128 KB

    transpose_w<<<dim3((1024 * 72 + 255) / 256), dim3(256), 0, stream>>>(
        W_ih, W_hh, wihT, whhT);

    lstm_persist<<<dim3(Bsz / RT), dim3(NTHR), 0, stream>>>(
        x, wihT, whhT, b_ih, b_hh, W_fc, b_fc, out);
}

// Round 8
// 3905.935 us; speedup vs baseline: 1.3676x; 1.3676x over previous
//
#include <hip/hip_runtime.h>

#define Bsz 2048
#define Ssz 96
#define Fsz 32
#define Hsz 256
#define Osz 6
#define LAsz 32
#define RT 8                  // batch rows per block; grid = 256 = 1 block/CU
#define NSTEP (Ssz + LAsz)
#define NTHR 512              // thread = (channel j, K-half q); 8 waves = 2/SIMD
#define KSPLIT 112            // q0: F-part + h[0:112); q1: h[112:256)  (18 iters each)

// ---------- accurate f64 exp (|rel err| ~1e-14) ----------
__device__ __forceinline__ double exp_d(double x) {
    x = fmin(fmax(x, -700.0), 700.0);
    const double LOG2E = 1.4426950408889634074;
    const double LN2HI = 6.93147180369123816490e-01;
    const double LN2LO = 1.90821492927058770002e-10;
    double n = __builtin_rint(x * LOG2E);
    double r = fma(-n, LN2HI, x);
    r = fma(-n, LN2LO, r);
    double p = 2.5052108385441718775e-08;
    p = fma(p, r, 2.7557319223985890653e-07);
    p = fma(p, r, 2.7557319223985892511e-06);
    p = fma(p, r, 2.4801587301587301566e-05);
    p = fma(p, r, 1.9841269841269841253e-04);
    p = fma(p, r, 1.3888888888888889419e-03);
    p = fma(p, r, 8.3333333333333332177e-03);
    p = fma(p, r, 4.1666666666666664354e-02);
    p = fma(p, r, 1.6666666666666665741e-01);
    p = fma(p, r, 5.0e-01);
    p = fma(p, r, 1.0);
    p = fma(p, r, 1.0);
    long long bits = (long long)(1023 + (int)n) << 52;
    return p * __longlong_as_double(bits);
}

// f64 reciprocal via f32 seed + 3 Newton steps, avoids slow f64 div
__device__ __forceinline__ double recip_d(double y) {
    double r = (double)(1.0f / (float)y);
    r = fma(fma(-y, r, 1.0), r, r);
    r = fma(fma(-y, r, 1.0), r, r);
    r = fma(fma(-y, r, 1.0), r, r);
    return r;
}
__device__ __forceinline__ double sigmoid_d(double x) { return recip_d(1.0 + exp_d(-x)); }
__device__ __forceinline__ double tanh_d(double x) {
    double ax = fabs(x);
    double t = exp_d(-2.0 * ax);
    double r = (1.0 - t) * recip_d(1.0 + t);
    return x >= 0.0 ? r : -r;
}

// ---------- pre-pass: transpose weights into k-major float4 tiles ----------
__global__ void transpose_w(const float* __restrict__ W_ih,
                            const float* __restrict__ W_hh,
                            float4* __restrict__ wihT,
                            float4* __restrict__ whhT)
{
    int i = blockIdx.x * 256 + threadIdx.x;   // 1024 * 72 total
    if (i >= 1024 * 72) return;
    int gr = i / 72, s = i - gr * 72;
    if (s < 8) {
        const float* p = W_ih + (size_t)gr * Fsz + s * 4;
        wihT[s * 1024 + gr] = make_float4(p[0], p[1], p[2], p[3]);
    } else {
        int k4 = s - 8;
        const float* p = W_hh + (size_t)gr * Hsz + k4 * 4;
        whhT[k4 * 1024 + gr] = make_float4(p[0], p[1], p[2], p[3]);
    }
}

// 8 ascending-k FMAs for one gate accumulator
#define DOT8(accv, WA, WB)                              \
    accv = fma((double)WA.x, h01.x, accv);              \
    accv = fma((double)WA.y, h01.y, accv);              \
    accv = fma((double)WA.z, h23.x, accv);              \
    accv = fma((double)WA.w, h23.y, accv);              \
    accv = fma((double)WB.x, h45.x, accv);              \
    accv = fma((double)WB.y, h45.y, accv);              \
    accv = fma((double)WB.z, h67.x, accv);              \
    accv = fma((double)WB.w, h67.y, accv);

__global__ __launch_bounds__(NTHR, 2) void lstm_persist(
    const float* __restrict__ x,
    const float4* __restrict__ wihT, const float4* __restrict__ whhT,
    const float* __restrict__ b_ih, const float* __restrict__ b_hh,
    const float* __restrict__ W_fc, const float* __restrict__ b_fc,
    float* __restrict__ out)
{
    __shared__ __align__(16) double h_lds[RT][Hsz];     // 16 KB
    __shared__ __align__(16) double x_lds[RT][Fsz];     // 2 KB
    __shared__ double o_lds[RT][Osz];
    __shared__ float  wfc_lds[Osz * Hsz];               // 6 KB
    __shared__ double xch[2][16][Hsz + 1];              // 65.8 KB partial exchange

    const int tid  = threadIdx.x;
    const int row0 = blockIdx.x * RT;
    const int j    = tid & (Hsz - 1);                    // gate-channel owned
    const int q    = tid >> 8;                           // K-half (wave-uniform)

    for (int i = tid; i < RT * Hsz; i += NTHR) ((double*)h_lds)[i] = 0.0;
    for (int i = tid; i < Osz * Hsz; i += NTHR) wfc_lds[i] = W_fc[i];

    const double bias0 = (double)b_ih[0 * Hsz + j] + (double)b_hh[0 * Hsz + j];
    const double bias1 = (double)b_ih[1 * Hsz + j] + (double)b_hh[1 * Hsz + j];
    const double bias2 = (double)b_ih[2 * Hsz + j] + (double)b_hh[2 * Hsz + j];
    const double bias3 = (double)b_ih[3 * Hsz + j] + (double)b_hh[3 * Hsz + j];

    double c_reg[4];                 // c for finalized rows (q0: 0-3, q1: 4-7)
    #pragma unroll
    for (int r = 0; r < 4; ++r) c_reg[r] = 0.0;

    __syncthreads();

    for (int t = 0; t < NSTEP; ++t) {
        // ---- stage x[:, t (or t-Ssz), :]; fuse look-ahead o replacement ----
        if (tid < RT * Fsz) {
            int r = tid >> 5, f = tid & 31;
            int ts = (t < Ssz) ? t : (t - Ssz);
            double v;
            if (t >= Ssz && f < Osz) v = o_lds[r][f];
            else v = (double)x[((size_t)(row0 + r) * Ssz + ts) * Fsz + f];
            x_lds[r][f] = v;
        }
        __syncthreads();                                 // A: x staged, h final

        // accA = rows 0-3, accB = rows 4-7 — ALL register indices compile-time
        double accA[4][4], accB[4][4];
        {
            const bool own0 = (q == 0);
            #pragma unroll
            for (int rr = 0; rr < 4; ++rr) {
                accA[0][rr] = own0 ? bias0 : 0.0;  accB[0][rr] = own0 ? 0.0 : bias0;
                accA[1][rr] = own0 ? bias1 : 0.0;  accB[1][rr] = own0 ? 0.0 : bias1;
                accA[2][rr] = own0 ? bias2 : 0.0;  accB[2][rr] = own0 ? 0.0 : bias2;
                accA[3][rr] = own0 ? bias3 : 0.0;  accB[3][rr] = own0 ? 0.0 : bias3;
            }
        }

        // ---- F part (q==0 only): gates += W_ih . x ----
        if (q == 0) {
            #pragma unroll 1
            for (int k0 = 0; k0 < Fsz; k0 += 8) {
                const int s = k0 >> 2;
                float4 wa[4], wb[4];
                #pragma unroll
                for (int g = 0; g < 4; ++g) {
                    wa[g] = wihT[(size_t)s * 1024 + (g << 8) + j];
                    wb[g] = wihT[(size_t)(s + 1) * 1024 + (g << 8) + j];
                }
                #pragma unroll
                for (int rr = 0; rr < 4; ++rr) {
                    double2 h01 = *(const double2*)&x_lds[rr][k0];
                    double2 h23 = *(const double2*)&x_lds[rr][k0 + 2];
                    double2 h45 = *(const double2*)&x_lds[rr][k0 + 4];
                    double2 h67 = *(const double2*)&x_lds[rr][k0 + 6];
                    DOT8(accA[0][rr], wa[0], wb[0]);
                    DOT8(accA[1][rr], wa[1], wb[1]);
                    DOT8(accA[2][rr], wa[2], wb[2]);
                    DOT8(accA[3][rr], wa[3], wb[3]);
                }
                #pragma unroll
                for (int rr = 0; rr < 4; ++rr) {
                    double2 h01 = *(const double2*)&x_lds[4 + rr][k0];
                    double2 h23 = *(const double2*)&x_lds[4 + rr][k0 + 2];
                    double2 h45 = *(const double2*)&x_lds[4 + rr][k0 + 4];
                    double2 h67 = *(const double2*)&x_lds[4 + rr][k0 + 6];
                    DOT8(accB[0][rr], wa[0], wb[0]);
                    DOT8(accB[1][rr], wa[1], wb[1]);
                    DOT8(accB[2][rr], wa[2], wb[2]);
                    DOT8(accB[3][rr], wa[3], wb[3]);
                }
            }
        }

        // ---- H part: this K-half's slice (runtime bounds, static reg indices) ----
        {
            const int kb = q ? KSPLIT : 0;
            const int ke = q ? Hsz : KSPLIT;
            #pragma unroll 1
            for (int k0 = kb; k0 < ke; k0 += 8) {
                const int s = k0 >> 2;
                float4 wa[4], wb[4];
                #pragma unroll
                for (int g = 0; g < 4; ++g) {
                    wa[g] = whhT[(size_t)s * 1024 + (g << 8) + j];
                    wb[g] = whhT[(size_t)(s + 1) * 1024 + (g << 8) + j];
                }
                #pragma unroll
                for (int rr = 0; rr < 4; ++rr) {
                    double2 h01 = *(const double2*)&h_lds[rr][k0];
                    double2 h23 = *(const double2*)&h_lds[rr][k0 + 2];
                    double2 h45 = *(const double2*)&h_lds[rr][k0 + 4];
                    double2 h67 = *(const double2*)&h_lds[rr][k0 + 6];
                    DOT8(accA[0][rr], wa[0], wb[0]);
                    DOT8(accA[1][rr], wa[1], wb[1]);
                    DOT8(accA[2][rr], wa[2], wb[2]);
                    DOT8(accA[3][rr], wa[3], wb[3]);
                }
                #pragma unroll
                for (int rr = 0; rr < 4; ++rr) {
                    double2 h01 = *(const double2*)&h_lds[4 + rr][k0];
                    double2 h23 = *(const double2*)&h_lds[4 + rr][k0 + 2];
                    double2 h45 = *(const double2*)&h_lds[4 + rr][k0 + 4];
                    double2 h67 = *(const double2*)&h_lds[4 + rr][k0 + 6];
                    DOT8(accB[0][rr], wa[0], wb[0]);
                    DOT8(accB[1][rr], wa[1], wb[1]);
                    DOT8(accB[2][rr], wa[2], wb[2]);
                    DOT8(accB[3][rr], wa[3], wb[3]);
                }
            }
        }

        // ---- publish partials for the rows the OTHER half finalizes ----
        if (q == 0) {
            #pragma unroll
            for (int g = 0; g < 4; ++g)
                #pragma unroll
                for (int rr = 0; rr < 4; ++rr)
                    xch[0][g * 4 + rr][j] = accB[g][rr];
        } else {
            #pragma unroll
            for (int g = 0; g < 4; ++g)
                #pragma unroll
                for (int rr = 0; rr < 4; ++rr)
                    xch[1][g * 4 + rr][j] = accA[g][rr];
        }
        __syncthreads();                                 // B: partials published

        // ---- combine + activations; update c (regs) and h (LDS) ----
        if (q == 0) {
            #pragma unroll
            for (int rr = 0; rr < 4; ++rr) {
                double t0 = accA[0][rr] + xch[1][0 * 4 + rr][j];
                double t1 = accA[1][rr] + xch[1][1 * 4 + rr][j];
                double t2 = accA[2][rr] + xch[1][2 * 4 + rr][j];
                double t3 = accA[3][rr] + xch[1][3 * 4 + rr][j];
                double si = sigmoid_d(t0);
                double sf = sigmoid_d(t1);
                double tg = tanh_d(t2);
                double so = sigmoid_d(t3);
                double cn = fma(sf, c_reg[rr], si * tg);
                c_reg[rr] = cn;
                h_lds[rr][j] = so * tanh_d(cn);
            }
        } else {
            #pragma unroll
            for (int rr = 0; rr < 4; ++rr) {
                double t0 = accB[0][rr] + xch[0][0 * 4 + rr][j];
                double t1 = accB[1][rr] + xch[0][1 * 4 + rr][j];
                double t2 = accB[2][rr] + xch[0][2 * 4 + rr][j];
                double t3 = accB[3][rr] + xch[0][3 * 4 + rr][j];
                double si = sigmoid_d(t0);
                double sf = sigmoid_d(t1);
                double tg = tanh_d(t2);
                double so = sigmoid_d(t3);
                double cn = fma(sf, c_reg[rr], si * tg);
                c_reg[rr] = cn;
                h_lds[4 + rr][j] = so * tanh_d(cn);
            }
        }

        // ---- readout: wave w owns row w (8 waves, 8 rows) ----
        if (t >= Ssz - 1) {
            __syncthreads();                              // C: h complete
            const int w    = tid >> 6;                    // row 0..7
            const int lane = tid & 63;
            double a0 = 0.0, a1 = 0.0, a2 = 0.0, a3 = 0.0, a4 = 0.0, a5 = 0.0;
            #pragma unroll
            for (int m = 0; m < 4; ++m) {
                int k = lane + 64 * m;
                double hv = h_lds[w][k];
                bool b = hv > 0.0;
                a0 += b ? (double)wfc_lds[0 * Hsz + k] : 0.0;
                a1 += b ? (double)wfc_lds[1 * Hsz + k] : 0.0;
                a2 += b ? (double)wfc_lds[2 * Hsz + k] : 0.0;
                a3 += b ? (double)wfc_lds[3 * Hsz + k] : 0.0;
                a4 += b ? (double)wfc_lds[4 * Hsz + k] : 0.0;
                a5 += b ? (double)wfc_lds[5 * Hsz + k] : 0.0;
            }
            #pragma unroll
            for (int off = 32; off >= 1; off >>= 1) {
                a0 += __shfl_down(a0, off, 64);
                a1 += __shfl_down(a1, off, 64);
                a2 += __shfl_down(a2, off, 64);
                a3 += __shfl_down(a3, off, 64);
                a4 += __shfl_down(a4, off, 64);
                a5 += __shfl_down(a5, off, 64);
            }
            if (lane == 0) {
                size_t base = ((size_t)(row0 + w) * (LAsz + 1) + (t - (Ssz - 1))) * Osz;
                double o;
                o = (double)b_fc[0] + a0; o_lds[w][0] = o; out[base + 0] = (float)o;
                o = (double)b_fc[1] + a1; o_lds[w][1] = o; out[base + 1] = (float)o;
                o = (double)b_fc[2] + a2; o_lds[w][2] = o; out[base + 2] = (float)o;
                o = (double)b_fc[3] + a3; o_lds[w][3] = o; out[base + 3] = (float)o;
                o = (double)b_fc[4] + a4; o_lds[w][4] = o; out[base + 4] = (float)o;
                o = (double)b_fc[5] + a5; o_lds[w][5] = o; out[base + 5] = (float)o;
            }
            __syncthreads();                              // D: o_lds published
        }
        // non-readout steps: next iteration's barrier A orders h/xch writes vs reads
    }
}

extern "C" void kernel_launch(void* const* d_in, const int* in_sizes, int n_in,
                              void* d_out, int out_size, void* d_ws, size_t ws_size,
                              hipStream_t stream)
{
    const float* x    = (const float*)d_in[0];
    const float* W_ih = (const float*)d_in[1];
    const float* W_hh = (const float*)d_in[2];
    const float* b_ih = (const float*)d_in[3];
    const float* b_hh = (const float*)d_in[4];
    const float* W_fc = (const float*)d_in[5];
    const float* b_fc = (const float*)d_in[6];
    float* out = (float*)d_out;

    float4* whhT = (float4*)d_ws;                 // 64*1024 float4 = 1 MB
    float4* wihT = whhT + 64 * 1024;              // 8*1024 float4 = 128 KB

    transpose_w<<<dim3((1024 * 72 + 255) / 256), dim3(256), 0, stream>>>(
        W_ih, W_hh, wihT, whhT);

    lstm_persist<<<dim3(Bsz / RT), dim3(NTHR), 0, stream>>>(
        x, wihT, whhT, b_ih, b_hh, W_fc, b_fc, out);
}